// Round 1
// baseline (185.500 us; speedup 1.0000x reference)
//
#include <hip/hip_runtime.h>
#include <math.h>

// EdgeDetection: fused gray -> gauss3x3(sigma=0.8, reflect101) -> scharr -> L2 mag
// Input  [B,3,1024,1024] f32, Output [B,3,1024,1024] f32 (mag replicated per channel)

#define IMG_H 1024
#define IMG_W 1024
#define TH 16
#define TW 128
#define GY (TH + 4)   // gray tile rows   (20)
#define GX (TW + 4)   // gray tile cols   (132)
#define BYR (TH + 2)  // blur tile rows   (18)
#define BXC (TW + 2)  // blur tile cols   (130)

// 1D gaussian weights for sigma=0.8, k=3: e = exp(-1/(2*0.64)) = exp(-0.78125)
// w1 = e/(1+2e), w0 = 1/(1+2e)
#define GW0 0.52201125f
#define GW1 0.23899437f

__global__ __launch_bounds__(256)
void edge_kernel(const float* __restrict__ in, float* __restrict__ out, int B) {
    __shared__ float sg[GY][GX];
    __shared__ float sb[BYR][BXC];

    const int tid = threadIdx.x;
    const int x0 = blockIdx.x * TW;
    const int y0 = blockIdx.y * TH;
    const int b  = blockIdx.z;

    const size_t plane = (size_t)IMG_H * IMG_W;
    const float* pr = in + (size_t)b * 3 * plane;
    const float* pg = pr + plane;
    const float* pb = pg + plane;

    // ---- stage gray tile with reflect-101 ----
    for (int i = tid; i < GY * GX; i += 256) {
        int gy = i / GX;
        int gx = i - gy * GX;
        int y = y0 - 2 + gy;
        int x = x0 - 2 + gx;
        y = (y < 0) ? -y : ((y >= IMG_H) ? (2 * IMG_H - 2 - y) : y);
        x = (x < 0) ? -x : ((x >= IMG_W) ? (2 * IMG_W - 2 - x) : x);
        int idx = y * IMG_W + x;
        sg[gy][gx] = 0.299f * pr[idx] + 0.587f * pg[idx] + 0.114f * pb[idx];
    }
    __syncthreads();

    // ---- 3x3 gaussian blur (separable weights) into sb ----
    for (int i = tid; i < BYR * BXC; i += 256) {
        int by = i / BXC;
        int bx = i - by * BXC;
        float h0 = GW1 * sg[by    ][bx] + GW0 * sg[by    ][bx + 1] + GW1 * sg[by    ][bx + 2];
        float h1 = GW1 * sg[by + 1][bx] + GW0 * sg[by + 1][bx + 1] + GW1 * sg[by + 1][bx + 2];
        float h2 = GW1 * sg[by + 2][bx] + GW0 * sg[by + 2][bx + 1] + GW1 * sg[by + 2][bx + 2];
        sb[by][bx] = GW1 * h0 + GW0 * h1 + GW1 * h2;
    }
    __syncthreads();

    // ---- scharr + magnitude, write 3 channels ----
    const int tx  = tid & (TW - 1);   // 0..127
    const int ty0 = tid >> 7;         // 0..1
    float* po = out + (size_t)b * 3 * plane;
    for (int ty = ty0; ty < TH; ty += 2) {
        float a00 = sb[ty    ][tx], a01 = sb[ty    ][tx + 1], a02 = sb[ty    ][tx + 2];
        float a10 = sb[ty + 1][tx],                           a12 = sb[ty + 1][tx + 2];
        float a20 = sb[ty + 2][tx], a21 = sb[ty + 2][tx + 1], a22 = sb[ty + 2][tx + 2];
        float sx = 3.0f * (a02 - a00) + 10.0f * (a12 - a10) + 3.0f * (a22 - a20);
        float sy = 3.0f * (a20 - a00) + 10.0f * (a21 - a01) + 3.0f * (a22 - a02);
        float mag = sqrtf(sx * sx + sy * sy);
        size_t o = (size_t)(y0 + ty) * IMG_W + (x0 + tx);
        po[o]             = mag;
        po[o + plane]     = mag;
        po[o + 2 * plane] = mag;
    }
}

extern "C" void kernel_launch(void* const* d_in, const int* in_sizes, int n_in,
                              void* d_out, int out_size, void* d_ws, size_t ws_size,
                              hipStream_t stream) {
    const float* in = (const float*)d_in[0];
    float* out = (float*)d_out;
    const int B = in_sizes[0] / (3 * IMG_H * IMG_W);
    dim3 grid(IMG_W / TW, IMG_H / TH, B);
    edge_kernel<<<grid, dim3(256), 0, stream>>>(in, out, B);
}

// Round 2
// 182.874 us; speedup vs baseline: 1.0144x; 1.0144x over previous
//
#include <hip/hip_runtime.h>
#include <math.h>

// EdgeDetection: fused gray -> gauss3x3(sigma=0.8, reflect101) -> scharr -> L2 mag
// Input  [B,3,1024,1024] f32, Output [B,3,1024,1024] f32 (mag replicated per channel)
// R1: full float4 vectorization of global loads/stores + ds_read_b128 LDS reads.

#define IMG_H 1024
#define IMG_W 1024
#define TH 16
#define TW 128

#define GYR (TH + 4)    // gray rows            20
#define GXD (TW + 8)    // gray data cols       136  (x0-4 .. x0+131)
#define GXS (GXD + 4)   // gray LDS stride      140  (keeps 16B align: 140*4=560)
#define BYR (TH + 2)    // blur rows            18
#define BXS (TW + 4)    // blur cols/stride     132  (x0-1 .. x0+130; 132*4=528, 16B-mult)

// 1D gaussian weights, sigma=0.8 k=3: e=exp(-0.78125), w0=1/(1+2e), w1=e/(1+2e)
#define GW0 0.52201125f
#define GW1 0.23899437f

__device__ __forceinline__ int reflect101(int v, int n) {
    v = (v < 0) ? -v : v;
    return (v >= n) ? (2 * n - 2 - v) : v;
}

__global__ __launch_bounds__(256)
void edge_kernel(const float* __restrict__ in, float* __restrict__ out, int B) {
    __shared__ float sg[GYR][GXS];
    __shared__ float sb[BYR][BXS];

    const int tid = threadIdx.x;
    const int x0 = blockIdx.x * TW;
    const int y0 = blockIdx.y * TH;
    const int b  = blockIdx.z;

    const size_t plane = (size_t)IMG_H * IMG_W;
    const float* pr = in + (size_t)b * 3 * plane;
    const float* pg = pr + plane;
    const float* pb = pg + plane;

    // ---- stage gray tile (float4 loads; scalar reflect only at image x-edges) ----
    // items: 20 rows x 34 float4s
    for (int i = tid; i < GYR * (GXD / 4); i += 256) {
        int gy  = i / (GXD / 4);
        int gx4 = (i - gy * (GXD / 4)) * 4;
        int y = reflect101(y0 - 2 + gy, IMG_H);
        int x = x0 - 4 + gx4;
        float4 r4, g4, b4;
        if ((unsigned)x <= (unsigned)(IMG_W - 4)) {
            size_t o = (size_t)y * IMG_W + x;
            r4 = *(const float4*)(pr + o);
            g4 = *(const float4*)(pg + o);
            b4 = *(const float4*)(pb + o);
        } else {
            int xe0 = reflect101(x,     IMG_W), xe1 = reflect101(x + 1, IMG_W);
            int xe2 = reflect101(x + 2, IMG_W), xe3 = reflect101(x + 3, IMG_W);
            size_t ro = (size_t)y * IMG_W;
            r4 = make_float4(pr[ro+xe0], pr[ro+xe1], pr[ro+xe2], pr[ro+xe3]);
            g4 = make_float4(pg[ro+xe0], pg[ro+xe1], pg[ro+xe2], pg[ro+xe3]);
            b4 = make_float4(pb[ro+xe0], pb[ro+xe1], pb[ro+xe2], pb[ro+xe3]);
        }
        float4 gr;
        gr.x = 0.299f * r4.x + 0.587f * g4.x + 0.114f * b4.x;
        gr.y = 0.299f * r4.y + 0.587f * g4.y + 0.114f * b4.y;
        gr.z = 0.299f * r4.z + 0.587f * g4.z + 0.114f * b4.z;
        gr.w = 0.299f * r4.w + 0.587f * g4.w + 0.114f * b4.w;
        *(float4*)&sg[gy][gx4] = gr;
    }
    __syncthreads();

    // ---- 3x3 gaussian blur (separable), float4 granularity ----
    // blur col j (0..131) = abs x0-1+j ; needs sg cols j+2..j+4 ; 4 outs need j+2..j+7
    // items: 18 rows x 33 float4s
    for (int i = tid; i < BYR * (BXS / 4); i += 256) {
        int by  = i / (BXS / 4);
        int bx4 = (i - by * (BXS / 4)) * 4;
        float4 r0a = *(const float4*)&sg[by    ][bx4];
        float4 r0b = *(const float4*)&sg[by    ][bx4 + 4];
        float4 r1a = *(const float4*)&sg[by + 1][bx4];
        float4 r1b = *(const float4*)&sg[by + 1][bx4 + 4];
        float4 r2a = *(const float4*)&sg[by + 2][bx4];
        float4 r2b = *(const float4*)&sg[by + 2][bx4 + 4];
        float v2 = GW1 * (r0a.z + r2a.z) + GW0 * r1a.z;
        float v3 = GW1 * (r0a.w + r2a.w) + GW0 * r1a.w;
        float v4 = GW1 * (r0b.x + r2b.x) + GW0 * r1b.x;
        float v5 = GW1 * (r0b.y + r2b.y) + GW0 * r1b.y;
        float v6 = GW1 * (r0b.z + r2b.z) + GW0 * r1b.z;
        float v7 = GW1 * (r0b.w + r2b.w) + GW0 * r1b.w;
        float4 o;
        o.x = GW1 * (v2 + v4) + GW0 * v3;
        o.y = GW1 * (v3 + v5) + GW0 * v4;
        o.z = GW1 * (v4 + v6) + GW0 * v5;
        o.w = GW1 * (v5 + v7) + GW0 * v6;
        *(float4*)&sb[by][bx4] = o;
    }
    __syncthreads();

    // ---- scharr + magnitude; each thread: 4 consecutive pixels, 2 rows ----
    // pixel col c (0..127) -> sb cols c..c+2 ; 4 pixels c4..c4+3 -> sb cols c4..c4+5
    const int c4 = (tid & 31) * 4;
    const int ty_base = tid >> 5;  // 0..7
    float* po = out + (size_t)b * 3 * plane;
    for (int ty = ty_base; ty < TH; ty += 8) {
        float4 t0a = *(const float4*)&sb[ty    ][c4];
        float4 t0b = *(const float4*)&sb[ty    ][c4 + 4];
        float4 t1a = *(const float4*)&sb[ty + 1][c4];
        float4 t1b = *(const float4*)&sb[ty + 1][c4 + 4];
        float4 t2a = *(const float4*)&sb[ty + 2][c4];
        float4 t2b = *(const float4*)&sb[ty + 2][c4 + 4];
        float r0[6] = {t0a.x, t0a.y, t0a.z, t0a.w, t0b.x, t0b.y};
        float r1[6] = {t1a.x, t1a.y, t1a.z, t1a.w, t1b.x, t1b.y};
        float r2[6] = {t2a.x, t2a.y, t2a.z, t2a.w, t2b.x, t2b.y};
        float4 mag;
        float* mp = &mag.x;
        #pragma unroll
        for (int k = 0; k < 4; ++k) {
            float sx = 3.0f * (r0[k+2] - r0[k]) + 10.0f * (r1[k+2] - r1[k]) + 3.0f * (r2[k+2] - r2[k]);
            float sy = 3.0f * (r2[k]   - r0[k]) + 10.0f * (r2[k+1] - r0[k+1]) + 3.0f * (r2[k+2] - r0[k+2]);
            mp[k] = sqrtf(sx * sx + sy * sy);
        }
        size_t o = (size_t)(y0 + ty) * IMG_W + (x0 + c4);
        *(float4*)(po + o)             = mag;
        *(float4*)(po + o + plane)     = mag;
        *(float4*)(po + o + 2 * plane) = mag;
    }
}

extern "C" void kernel_launch(void* const* d_in, const int* in_sizes, int n_in,
                              void* d_out, int out_size, void* d_ws, size_t ws_size,
                              hipStream_t stream) {
    const float* in = (const float*)d_in[0];
    float* out = (float*)d_out;
    const int B = in_sizes[0] / (3 * IMG_H * IMG_W);
    dim3 grid(IMG_W / TW, IMG_H / TH, B);
    edge_kernel<<<grid, dim3(256), 0, stream>>>(in, out, B);
}

// Round 3
// 178.371 us; speedup vs baseline: 1.0400x; 1.0252x over previous
//
#include <hip/hip_runtime.h>
#include <math.h>

// EdgeDetection: fused gray -> gauss3x3(sigma=0.8) -> scharr -> L2 mag, reflect-101
// R2: single-barrier version. Gauss∘Scharr composed into separable 5-tap kernels:
//   sx = (vertical [3,10,3]*g) x (horizontal [-1,0,1]*g)
//   sy = (vertical [-1,0,1]*g) x (horizontal [3,10,3]*g)
// One LDS array (gray only), 128x32 tile, 16 px/thread, deep staging load pipeline.

#define IMG_H 1024
#define IMG_W 1024
#define TH 32
#define TW 128
#define GYR (TH + 4)      // 36 gray rows  (y0-2 .. y0+33)
#define GXD 136           // gray cols = stride (x0-4 .. x0+131), 136*4 B = 16B-mult
#define NIT ((GYR * (GXD/4) + 255) / 256)   // 5 staging iterations
#define NITEMS (GYR * (GXD/4))              // 1224

// 1D gaussian sigma=0.8 k=3: e=exp(-0.78125); W0=1/(1+2e), W1=e/(1+2e)
#define W0 0.52201125f
#define W1 0.23899437f
// composite smooth taps a = conv([3,10,3],[W1,W0,W1]) (symmetric):
#define AV0 0.71698311f   // 3*W1
#define AV1 3.95597745f   // 3*W0 + 10*W1
#define AV2 6.65407872f   // 10*W0 + 6*W1
// composite deriv taps d = conv([-1,0,1],[W1,W0,W1]) = [-W1,-W0,0,W0,W1]

__device__ __forceinline__ int reflect101(int v, int n) {
    v = (v < 0) ? -v : v;
    return (v >= n) ? (2 * n - 2 - v) : v;
}

__global__ __launch_bounds__(256)
void edge_kernel(const float* __restrict__ in, float* __restrict__ out, int B) {
    __shared__ float sg[GYR][GXD];

    const int tid = threadIdx.x;
    const int x0 = blockIdx.x * TW;
    const int y0 = blockIdx.y * TH;
    const int b  = blockIdx.z;

    const size_t plane = (size_t)IMG_H * IMG_W;
    const float* pr = in + (size_t)b * 3 * plane;
    const float* pg = pr + plane;
    const float* pb = pg + plane;

    // ---- stage gray tile: two-phase (issue all loads, then convert+write) ----
    float4 R[NIT], G[NIT], Bv[NIT];
    #pragma unroll
    for (int it = 0; it < NIT; ++it) {
        int i = tid + it * 256;
        if (i < NITEMS) {
            int gy  = i / (GXD / 4);
            int gx4 = (i - gy * (GXD / 4)) * 4;
            int y = reflect101(y0 - 2 + gy, IMG_H);
            int x = x0 - 4 + gx4;
            if ((unsigned)x <= (unsigned)(IMG_W - 4)) {
                size_t o = (size_t)y * IMG_W + x;
                R[it]  = *(const float4*)(pr + o);
                G[it]  = *(const float4*)(pg + o);
                Bv[it] = *(const float4*)(pb + o);
            } else {
                int xe0 = reflect101(x,     IMG_W), xe1 = reflect101(x + 1, IMG_W);
                int xe2 = reflect101(x + 2, IMG_W), xe3 = reflect101(x + 3, IMG_W);
                size_t ro = (size_t)y * IMG_W;
                R[it]  = make_float4(pr[ro+xe0], pr[ro+xe1], pr[ro+xe2], pr[ro+xe3]);
                G[it]  = make_float4(pg[ro+xe0], pg[ro+xe1], pg[ro+xe2], pg[ro+xe3]);
                Bv[it] = make_float4(pb[ro+xe0], pb[ro+xe1], pb[ro+xe2], pb[ro+xe3]);
            }
        }
    }
    #pragma unroll
    for (int it = 0; it < NIT; ++it) {
        int i = tid + it * 256;
        if (i < NITEMS) {
            int gy  = i / (GXD / 4);
            int gx4 = (i - gy * (GXD / 4)) * 4;
            float4 gr;
            gr.x = 0.299f * R[it].x + 0.587f * G[it].x + 0.114f * Bv[it].x;
            gr.y = 0.299f * R[it].y + 0.587f * G[it].y + 0.114f * Bv[it].y;
            gr.z = 0.299f * R[it].z + 0.587f * G[it].z + 0.114f * Bv[it].z;
            gr.w = 0.299f * R[it].w + 0.587f * G[it].w + 0.114f * Bv[it].w;
            *(float4*)&sg[gy][gx4] = gr;
        }
    }
    __syncthreads();

    // ---- compute: each thread does 4 rows x 4 cols via 5-row (hs,hd) ring ----
    const int tx  = tid & 31;       // col group
    const int tyg = tid >> 5;       // 0..7
    const int c4  = tx * 4;         // output cols x0+c4 .. x0+c4+3
    const int r0  = tyg * 4;        // output rows y0+r0 .. y0+r0+3

    float hs[5][4], hd[5][4];

    auto hrow = [&](int rr, float* HS, float* HD) {
        const float* row = &sg[rr][c4];
        float4 ga = *(const float4*)(row);
        float4 gb = *(const float4*)(row + 4);
        float4 gc = *(const float4*)(row + 8);
        float g[12] = {ga.x, ga.y, ga.z, ga.w, gb.x, gb.y, gb.z, gb.w,
                       gc.x, gc.y, gc.z, gc.w};
        #pragma unroll
        for (int k = 0; k < 4; ++k) {
            HS[k] = AV0 * (g[k+2] + g[k+6]) + AV1 * (g[k+3] + g[k+5]) + AV2 * g[k+4];
            HD[k] = W1 * (g[k+6] - g[k+2]) + W0 * (g[k+5] - g[k+3]);
        }
    };

    #pragma unroll
    for (int s = 0; s < 5; ++s) hrow(r0 + s, hs[s], hd[s]);

    float* po = out + (size_t)b * 3 * plane;
    #pragma unroll
    for (int t = 0; t < 4; ++t) {
        if (t > 0) hrow(r0 + 4 + t, hs[(t + 4) % 5], hd[(t + 4) % 5]);
        const int i0 = t % 5, i1 = (t+1) % 5, i2 = (t+2) % 5, i3 = (t+3) % 5, i4 = (t+4) % 5;
        float4 mag;
        float* mp = &mag.x;
        #pragma unroll
        for (int k = 0; k < 4; ++k) {
            float sx = AV0 * (hd[i0][k] + hd[i4][k]) + AV1 * (hd[i1][k] + hd[i3][k]) + AV2 * hd[i2][k];
            float sy = W1 * (hs[i4][k] - hs[i0][k]) + W0 * (hs[i3][k] - hs[i1][k]);
            mp[k] = sqrtf(sx * sx + sy * sy);
        }
        size_t o = (size_t)(y0 + r0 + t) * IMG_W + (x0 + c4);
        *(float4*)(po + o)             = mag;
        *(float4*)(po + o + plane)     = mag;
        *(float4*)(po + o + 2 * plane) = mag;
    }
}

extern "C" void kernel_launch(void* const* d_in, const int* in_sizes, int n_in,
                              void* d_out, int out_size, void* d_ws, size_t ws_size,
                              hipStream_t stream) {
    const float* in = (const float*)d_in[0];
    float* out = (float*)d_out;
    const int B = in_sizes[0] / (3 * IMG_H * IMG_W);
    dim3 grid(IMG_W / TW, IMG_H / TH, B);
    edge_kernel<<<grid, dim3(256), 0, stream>>>(in, out, B);
}